// Round 13
// baseline (3413.546 us; speedup 1.0000x reference)
//
#include <hip/hip_runtime.h>

// RNN: s_{t+1} = 0.9*s + 0.1*(relu(s@Wrec^T + (u+inz)@Winp^T) + rn)
// d_out = states (B,T,N) fp32 then outputs (B,T,1) fp32, flat-concat.
//
// R13: resident-W, n-partitioned, fused tag+payload IF exchange (R12,
// 2.99 ms) + BATCH-HALVED SKEWED PIPELINE to hide the IF round trip.
//   R12 counters: step 3.05 us, VALU ~1.1 us -> publish->poll RT (~1 us)
//   sits naked on the critical path. Split batches into halves h0={0,1},
//   h1={2,3}: fetch(h0) / phaseA(h0)+issue-pf(h1) / update+publish(h0) /
//   fetch(h1) / phaseA(h1)+issue-pf(h0,t+1) / update+publish(h1).
//   Each publish gets ~half a step of compute between it and its
//   consumer's poll; poll loads are issued under the FMA block (the
//   barrier's implicit vmcnt drain lands after compute). Re-poll loop
//   remains as the correctness net (first-try hit = common case).
//   Per-word WAR/parity proof is R12's, per half: writer overwrites tag
//   t-1 -> t+1 only after its half-h fetch of tag t, which implies every
//   peer published t (half h), which implies it consumed t-1 (half h).
//   Tags monotone; init kernel resets to -1 each call (0xAA poison also
//   parses negative) -> graph-replay-safe.
// out_proj projects outputs afterwards. Fallback R1-style kernel if ws
// is too small (< 1 MB).

#define NN 512
#define BB 128
#define TT 1000
#define NIN 6
#define PP 4                    // n-slices (WGs per group)
#define GG 4                    // batches per group
#define NGRP (BB / GG)          // 32 groups
#define NWG (PP * NGRP)         // 128 workgroups
#define SLICE (NN / PP)         // 128
#define XWORDS (2 * NGRP * GG * NN)          // 131072 words = 1 MB
#define WS_NEED (XWORDS * sizeof(unsigned long long))

typedef unsigned long long u64;

__global__ void init_xbuf(u64* xbuf) {
  const int i = blockIdx.x * 256 + threadIdx.x;
  if (i < XWORDS / 2) {
    xbuf[i] = 0xFFFFFFFF00000000ULL;
    xbuf[i + XWORDS / 2] = 0xFFFFFFFF00000000ULL;
  }
}

__device__ __forceinline__ float wave_sum(float v) {
  #pragma unroll
  for (int off = 32; off > 0; off >>= 1) v += __shfl_xor(v, off, 64);
  return v;
}

// empty asm with tied SCALAR outputs: values become opaque (non-remat).
__device__ __forceinline__ void pin4(float4& a, float4& b, float4& c, float4& d) {
  asm volatile("" : "+v"(a.x), "+v"(a.y), "+v"(a.z), "+v"(a.w),
                    "+v"(b.x), "+v"(b.y), "+v"(b.z), "+v"(b.w),
                    "+v"(c.x), "+v"(c.y), "+v"(c.z), "+v"(c.w),
                    "+v"(d.x), "+v"(d.y), "+v"(d.z), "+v"(d.w));
}

__device__ __forceinline__ u64 xld(const u64* p) {
  return __hip_atomic_load(p, __ATOMIC_RELAXED, __HIP_MEMORY_SCOPE_SYSTEM);
}
__device__ __forceinline__ void xst(u64* p, u64 v) {
  __hip_atomic_store(p, v, __ATOMIC_RELAXED, __HIP_MEMORY_SCOPE_SYSTEM);
}

__global__ __launch_bounds__(512, 1)
void rnn_skew(const float* __restrict__ u, const float* __restrict__ rnz,
              const float* __restrict__ inz, const float* __restrict__ Wrec,
              const float* __restrict__ Winp, const float* __restrict__ yinit,
              float* __restrict__ states, u64* __restrict__ xbuf) {
  const int tid = threadIdx.x;
  // bid remap: group's 4 WGs share bid&7 (locality hint only; protocol is
  // placement-independent -- all exchange goes through IF).
  const int xcd = blockIdx.x & 7;
  const int rest = blockIdx.x >> 3;     // 0..15
  const int p = rest & 3;               // my n-slice
  const int g = (rest >> 2) * 8 + xcd;  // my group 0..31

  // phase-A mapping: thread (nq, ks) = 4 n-rows x 32-k window
  const int nq = tid & 31;
  const int n0 = nq << 2;
  const int ks = tid >> 5;              // 0..15 (2 per wave -> broadcast)
  const int k0 = ks << 5;
  // update mapping (tid < 256): item (ubh, un) in each half
  const int ubh = (tid >> 7) & 1;
  const int un = tid & 127;
  const int ung = p * SLICE + un;
  // fetch word decode: i1 = tid (all), i2 = 512+tid (tid<256)
  const int q1 = (p + 1 + (tid >> 8)) & 3;
  const int fb1 = (tid & 255) >> 7;
  const int fun1 = tid & 127;
  const int q2 = (p + 3) & 3;
  const int fb2 = (tid >> 7) & 1;       // valid for tid<256
  const int fun2 = tid & 127;

  __shared__ __align__(16) float pred[16][2][SLICE];  // 16 KB
  __shared__ __align__(16) float s_all[GG][NN];       // 8 KB
  __shared__ float winp_s[SLICE][NIN];                // 3 KB
  __shared__ float ubuf[GG][NIN];

  // ---- one-time: W fragment (4 rows x 32 k), Winp, s_0 ----
  float4 w[4][8];
  #pragma unroll
  for (int i = 0; i < 4; ++i) {
    const float* wr = Wrec + (size_t)(p * SLICE + n0 + i) * NN + k0;
    #pragma unroll
    for (int q = 0; q < 8; ++q)
      w[i][q] = *reinterpret_cast<const float4*>(wr + 4 * q);
  }
  for (int i = tid; i < SLICE * NIN; i += 512) {
    const int r = i / NIN, j = i - r * NIN;
    winp_s[r][j] = Winp[(p * SLICE + r) * NIN + j];
  }
  for (int i = tid; i < GG * NN; i += 512)
    s_all[i >> 9][i & 511] = yinit[i & 511];
  {
    const int b = tid >> 7;  // 0..3
    states[(size_t)(g * GG + b) * TT * NN + ung] = yinit[ung];
  }
  float scurA = yinit[ung];  // half0 item (b = ubh)
  float scurB = scurA;       // half1 item (b = 2 + ubh)
  __syncthreads();

  u64 pfA = 0, pfB = 0;

  for (int t = 0; t < TT - 1; ++t) {
    const int par = t & 1;
    const u64* xbr = xbuf + ((size_t)par * NGRP + g) * GG * NN;
    u64* xbw = xbuf + ((size_t)((t + 1) & 1) * NGRP + g) * GG * NN;

    // pin W live (R6: unpinned W was re-streamed from L2 every step)
    #pragma unroll
    for (int i = 0; i < 4; ++i) {
      pin4(w[i][0], w[i][1], w[i][2], w[i][3]);
      pin4(w[i][4], w[i][5], w[i][6], w[i][7]);
    }

    // early per-step loads
    float rnzA = 0.f, rnzB = 0.f;
    if (tid < 256) {
      rnzA = rnz[((size_t)(g * GG + ubh) * TT + t) * NN + ung];
      rnzB = rnz[((size_t)(g * GG + 2 + ubh) * TT + t) * NN + ung];
    }
    if (tid < GG * NIN) {
      const int b = tid / NIN, j = tid - b * NIN;
      const size_t idx = ((size_t)(g * GG + b) * TT + t) * NIN + j;
      ubuf[b][j] = u[idx] + inz[idx];
    }

    // ---- h0 fetch-commit (words prefetched at end of prev iteration) ----
    if (t > 0) {
      const u64* a1p = xbr + fb1 * NN + q1 * SLICE + fun1;
      int tg = (int)(pfA >> 32);
      while (tg < t) { __builtin_amdgcn_s_sleep(1); pfA = xld(a1p); tg = (int)(pfA >> 32); }
      s_all[fb1][q1 * SLICE + fun1] = __uint_as_float((unsigned)pfA);
      if (tid < 256) {
        const u64* a2p = xbr + fb2 * NN + q2 * SLICE + fun2;
        tg = (int)(pfB >> 32);
        while (tg < t) { __builtin_amdgcn_s_sleep(1); pfB = xld(a2p); tg = (int)(pfB >> 32); }
        s_all[fb2][q2 * SLICE + fun2] = __uint_as_float((unsigned)pfB);
      }
    }
    __syncthreads();  // A0: s_all[b01] complete + ubuf visible

    // issue prefetch for h1 (current t) BEFORE the FMA block
    if (t > 0) {
      pfA = xld(xbr + (2 + fb1) * NN + q1 * SLICE + fun1);
      if (tid < 256) pfB = xld(xbr + (2 + fb2) * NN + q2 * SLICE + fun2);
      asm volatile("" ::: "memory");
    }

    // ---- phase A h0: b = 0,1 ----
    {
      float a0[2], a1[2], a2[2], a3[2];
      #pragma unroll
      for (int bh = 0; bh < 2; ++bh) { a0[bh] = 0.f; a1[bh] = 0.f; a2[bh] = 0.f; a3[bh] = 0.f; }
      #pragma unroll
      for (int bh = 0; bh < 2; ++bh) {
        #pragma unroll
        for (int q = 0; q < 8; ++q) {
          const float4 sv = *reinterpret_cast<const float4*>(&s_all[bh][k0 + 4 * q]);
          a0[bh] = fmaf(w[0][q].x, sv.x, a0[bh]); a0[bh] = fmaf(w[0][q].y, sv.y, a0[bh]);
          a0[bh] = fmaf(w[0][q].z, sv.z, a0[bh]); a0[bh] = fmaf(w[0][q].w, sv.w, a0[bh]);
          a1[bh] = fmaf(w[1][q].x, sv.x, a1[bh]); a1[bh] = fmaf(w[1][q].y, sv.y, a1[bh]);
          a1[bh] = fmaf(w[1][q].z, sv.z, a1[bh]); a1[bh] = fmaf(w[1][q].w, sv.w, a1[bh]);
          a2[bh] = fmaf(w[2][q].x, sv.x, a2[bh]); a2[bh] = fmaf(w[2][q].y, sv.y, a2[bh]);
          a2[bh] = fmaf(w[2][q].z, sv.z, a2[bh]); a2[bh] = fmaf(w[2][q].w, sv.w, a2[bh]);
          a3[bh] = fmaf(w[3][q].x, sv.x, a3[bh]); a3[bh] = fmaf(w[3][q].y, sv.y, a3[bh]);
          a3[bh] = fmaf(w[3][q].z, sv.z, a3[bh]); a3[bh] = fmaf(w[3][q].w, sv.w, a3[bh]);
        }
        *reinterpret_cast<float4*>(&pred[ks][bh][n0]) =
            make_float4(a0[bh], a1[bh], a2[bh], a3[bh]);
      }
    }
    __syncthreads();  // B0: pred h0 visible

    // ---- update h0 (b = ubh) ----
    if (tid < 256) {
      float pre = 0.f;
      #pragma unroll
      for (int q = 0; q < 16; ++q) pre += pred[q][ubh][un];
      #pragma unroll
      for (int j = 0; j < NIN; ++j) pre = fmaf(ubuf[ubh][j], winp_s[un][j], pre);
      const float sn = 0.9f * scurA + 0.1f * (fmaxf(pre, 0.f) + rnzA);
      states[((size_t)(g * GG + ubh) * TT + t + 1) * NN + ung] = sn;
      xst(xbw + ubh * NN + ung,
          ((u64)(unsigned)(t + 1) << 32) | __float_as_uint(sn));
      s_all[ubh][ung] = sn;
      scurA = sn;
    }

    // ---- h1 fetch-commit ----
    if (t > 0) {
      const u64* a1p = xbr + (2 + fb1) * NN + q1 * SLICE + fun1;
      int tg = (int)(pfA >> 32);
      while (tg < t) { __builtin_amdgcn_s_sleep(1); pfA = xld(a1p); tg = (int)(pfA >> 32); }
      s_all[2 + fb1][q1 * SLICE + fun1] = __uint_as_float((unsigned)pfA);
      if (tid < 256) {
        const u64* a2p = xbr + (2 + fb2) * NN + q2 * SLICE + fun2;
        tg = (int)(pfB >> 32);
        while (tg < t) { __builtin_amdgcn_s_sleep(1); pfB = xld(a2p); tg = (int)(pfB >> 32); }
        s_all[2 + fb2][q2 * SLICE + fun2] = __uint_as_float((unsigned)pfB);
      }
    }
    __syncthreads();  // A1: s_all[b23] complete

    // issue prefetch for h0 of t+1 (reads peer slices of xbw: disjoint
    // from my slice-p publishes)
    {
      pfA = xld((const u64*)xbw + fb1 * NN + q1 * SLICE + fun1);
      if (tid < 256) pfB = xld((const u64*)xbw + fb2 * NN + q2 * SLICE + fun2);
      asm volatile("" ::: "memory");
    }

    // ---- phase A h1: b = 2,3 ----
    {
      float a0[2], a1[2], a2[2], a3[2];
      #pragma unroll
      for (int bh = 0; bh < 2; ++bh) { a0[bh] = 0.f; a1[bh] = 0.f; a2[bh] = 0.f; a3[bh] = 0.f; }
      #pragma unroll
      for (int bh = 0; bh < 2; ++bh) {
        #pragma unroll
        for (int q = 0; q < 8; ++q) {
          const float4 sv = *reinterpret_cast<const float4*>(&s_all[2 + bh][k0 + 4 * q]);
          a0[bh] = fmaf(w[0][q].x, sv.x, a0[bh]); a0[bh] = fmaf(w[0][q].y, sv.y, a0[bh]);
          a0[bh] = fmaf(w[0][q].z, sv.z, a0[bh]); a0[bh] = fmaf(w[0][q].w, sv.w, a0[bh]);
          a1[bh] = fmaf(w[1][q].x, sv.x, a1[bh]); a1[bh] = fmaf(w[1][q].y, sv.y, a1[bh]);
          a1[bh] = fmaf(w[1][q].z, sv.z, a1[bh]); a1[bh] = fmaf(w[1][q].w, sv.w, a1[bh]);
          a2[bh] = fmaf(w[2][q].x, sv.x, a2[bh]); a2[bh] = fmaf(w[2][q].y, sv.y, a2[bh]);
          a2[bh] = fmaf(w[2][q].z, sv.z, a2[bh]); a2[bh] = fmaf(w[2][q].w, sv.w, a2[bh]);
          a3[bh] = fmaf(w[3][q].x, sv.x, a3[bh]); a3[bh] = fmaf(w[3][q].y, sv.y, a3[bh]);
          a3[bh] = fmaf(w[3][q].z, sv.z, a3[bh]); a3[bh] = fmaf(w[3][q].w, sv.w, a3[bh]);
        }
        *reinterpret_cast<float4*>(&pred[ks][bh][n0]) =
            make_float4(a0[bh], a1[bh], a2[bh], a3[bh]);
      }
    }
    __syncthreads();  // B1: pred h1 visible

    // ---- update h1 (b = 2 + ubh) ----
    if (tid < 256) {
      float pre = 0.f;
      #pragma unroll
      for (int q = 0; q < 16; ++q) pre += pred[q][ubh][un];
      #pragma unroll
      for (int j = 0; j < NIN; ++j) pre = fmaf(ubuf[2 + ubh][j], winp_s[un][j], pre);
      const float sn = 0.9f * scurB + 0.1f * (fmaxf(pre, 0.f) + rnzB);
      states[((size_t)(g * GG + 2 + ubh) * TT + t + 1) * NN + ung] = sn;
      xst(xbw + (2 + ubh) * NN + ung,
          ((u64)(unsigned)(t + 1) << 32) | __float_as_uint(sn));
      s_all[2 + ubh][ung] = sn;
      scurB = sn;
    }
    // no trailing barrier: next iteration's h0 fetch writes peer LDS
    // slices (disjoint from own-slice writes above); pred reuse is
    // fenced by A0+B0.
  }
}

// outputs[b][t] = dot(states[b][t][:], Wout) -- one wave per row
__global__ __launch_bounds__(256)
void out_proj(const float* __restrict__ states, const float* __restrict__ Wout,
              float* __restrict__ outputs) {
  const int lane = threadIdx.x & 63;
  const size_t row = (size_t)blockIdx.x * 4 + (threadIdx.x >> 6);
  if (row >= (size_t)BB * TT) return;
  const float* sr = states + row * NN;
  float acc = 0.f;
  #pragma unroll
  for (int h = 0; h < 2; ++h) {
    const float4 sv = *reinterpret_cast<const float4*>(sr + h * 256 + lane * 4);
    const float4 wv = *reinterpret_cast<const float4*>(Wout + h * 256 + lane * 4);
    acc = fmaf(sv.x, wv.x, acc);
    acc = fmaf(sv.y, wv.y, acc);
    acc = fmaf(sv.z, wv.z, acc);
    acc = fmaf(sv.w, wv.w, acc);
  }
  acc = wave_sum(acc);
  if (lane == 0) outputs[row] = acc;
}

// ---------------- fallback: proven R1 kernel (ws too small) ----------------
__global__ __launch_bounds__(512)
void rnn_fused(const float* __restrict__ u, const float* __restrict__ rnz,
               const float* __restrict__ inz, const float* __restrict__ Wsrc,
               const float* __restrict__ Winp, const float* __restrict__ Wout,
               const float* __restrict__ yinit,
               float* __restrict__ states, float* __restrict__ outputs) {
  const int tid = threadIdx.x;
  const int n4 = tid & 127;
  const int kc = tid >> 7;
  const int b0 = blockIdx.x * 2;
  const int b1 = b0 + 1;

  __shared__ __align__(16) float s[2][NN];
  __shared__ __align__(16) float red[2][128][20];
  __shared__ float ubf[2 * NIN];
  __shared__ float outred[2][8];

  float wi[NIN];
  #pragma unroll
  for (int j = 0; j < NIN; ++j) wi[j] = Winp[tid * NIN + j];
  const float wo = Wout[tid];
  const float yv = yinit[tid];

  s[0][tid] = yv;
  s[1][tid] = yv;
  states[(size_t)(b0 * TT) * NN + tid] = yv;
  states[(size_t)(b1 * TT) * NN + tid] = yv;
  {
    float pzz = wave_sum(yv * wo);
    if ((tid & 63) == 0) outred[0][tid >> 6] = pzz;
  }
  __syncthreads();
  if (tid < 2) {
    float a = 0.f;
    #pragma unroll
    for (int wq = 0; wq < 8; ++wq) a += outred[0][wq];
    outputs[(tid ? b1 : b0) * TT] = a;
  }
  __syncthreads();

  for (int t = 0; t < TT - 1; ++t) {
    const float rn0 = rnz[(size_t)(b0 * TT + t) * NN + tid];
    const float rn1 = rnz[(size_t)(b1 * TT + t) * NN + tid];
    float uv = 0.f;
    if (tid < 2 * NIN) {
      const int b = (tid < NIN) ? b0 : b1;
      const int j = (tid < NIN) ? tid : tid - NIN;
      const int idx = (b * TT + t) * NIN + j;
      uv = u[idx] + inz[idx];
    }
    float a0[4] = {0.f, 0.f, 0.f, 0.f};
    float a1[4] = {0.f, 0.f, 0.f, 0.f};
    const int kbase0 = kc * 128;
    #pragma unroll 4
    for (int j4 = 0; j4 < 32; ++j4) {
      const int kb = kbase0 + j4 * 4;
      const float4 s0v = *reinterpret_cast<const float4*>(&s[0][kb]);
      const float4 s1v = *reinterpret_cast<const float4*>(&s[1][kb]);
      const float s0a[4] = {s0v.x, s0v.y, s0v.z, s0v.w};
      const float s1a[4] = {s1v.x, s1v.y, s1v.z, s1v.w};
      #pragma unroll
      for (int jj = 0; jj < 4; ++jj) {
        const int k = kb + jj;
        const float* pw = Wsrc + (size_t)(n4 << 2) * NN + k;
        float4 wv;
        wv.x = pw[0]; wv.y = pw[NN]; wv.z = pw[2 * NN]; wv.w = pw[3 * NN];
        a0[0] = fmaf(wv.x, s0a[jj], a0[0]);
        a0[1] = fmaf(wv.y, s0a[jj], a0[1]);
        a0[2] = fmaf(wv.z, s0a[jj], a0[2]);
        a0[3] = fmaf(wv.w, s0a[jj], a0[3]);
        a1[0] = fmaf(wv.x, s1a[jj], a1[0]);
        a1[1] = fmaf(wv.y, s1a[jj], a1[1]);
        a1[2] = fmaf(wv.z, s1a[jj], a1[2]);
        a1[3] = fmaf(wv.w, s1a[jj], a1[3]);
      }
    }
    if (tid < 2 * NIN) ubf[tid] = uv;
    *reinterpret_cast<float4*>(&red[0][n4][kc << 2]) =
        make_float4(a0[0], a0[1], a0[2], a0[3]);
    *reinterpret_cast<float4*>(&red[1][n4][kc << 2]) =
        make_float4(a1[0], a1[1], a1[2], a1[3]);
    __syncthreads();
    const int n = tid;
    const int r = n >> 2, c = n & 3;
    float pre0 = (red[0][r][c] + red[0][r][4 + c]) +
                 (red[0][r][8 + c] + red[0][r][12 + c]);
    float pre1 = (red[1][r][c] + red[1][r][4 + c]) +
                 (red[1][r][8 + c] + red[1][r][12 + c]);
    #pragma unroll
    for (int j = 0; j < NIN; ++j) {
      pre0 = fmaf(ubf[j], wi[j], pre0);
      pre1 = fmaf(ubf[NIN + j], wi[j], pre1);
    }
    const float sn0 = 0.9f * s[0][n] + 0.1f * (fmaxf(pre0, 0.f) + rn0);
    const float sn1 = 0.9f * s[1][n] + 0.1f * (fmaxf(pre1, 0.f) + rn1);
    states[(size_t)(b0 * TT + t + 1) * NN + n] = sn0;
    states[(size_t)(b1 * TT + t + 1) * NN + n] = sn1;
    s[0][n] = sn0;
    s[1][n] = sn1;
    float p0 = wave_sum(sn0 * wo);
    float p1 = wave_sum(sn1 * wo);
    if ((tid & 63) == 0) {
      outred[0][tid >> 6] = p0;
      outred[1][tid >> 6] = p1;
    }
    __syncthreads();
    if (tid < 2) {
      float a = 0.f;
      #pragma unroll
      for (int wq = 0; wq < 8; ++wq) a += outred[tid][wq];
      outputs[(tid ? b1 : b0) * TT + t + 1] = a;
    }
  }
}

extern "C" void kernel_launch(void* const* d_in, const int* in_sizes, int n_in,
                              void* d_out, int out_size, void* d_ws, size_t ws_size,
                              hipStream_t stream) {
  const float* u    = (const float*)d_in[0];
  const float* rnz  = (const float*)d_in[1];
  const float* inz  = (const float*)d_in[2];
  const float* Wrec = (const float*)d_in[3];
  const float* Winp = (const float*)d_in[4];
  const float* Wout = (const float*)d_in[5];
  const float* yin  = (const float*)d_in[6];
  float* states  = (float*)d_out;
  float* outputs = states + (size_t)BB * TT * NN;

  if (ws_size >= WS_NEED) {
    u64* xbuf = (u64*)d_ws;
    init_xbuf<<<(XWORDS / 2 + 255) / 256, 256, 0, stream>>>(xbuf);
    rnn_skew<<<NWG, 512, 0, stream>>>(u, rnz, inz, Wrec, Winp, yin,
                                      states, xbuf);
    out_proj<<<(BB * TT + 3) / 4, 256, 0, stream>>>(states, Wout, outputs);
  } else {
    rnn_fused<<<BB / 2, 512, 0, stream>>>(u, rnz, inz, Wrec, Winp, Wout,
                                          yin, states, outputs);
  }
}